// Round 3
// baseline (389.783 us; speedup 1.0000x reference)
//
#include <hip/hip_runtime.h>
#include <stdint.h>

#define S_LEN 2048
#define D_EMBD 1024
#define N_HEADS 16
#define D_HEAD 64
#define B_SZ 4
#define M_TOT (B_SZ * S_LEN)   // 8192

typedef __bf16 bf16x8 __attribute__((ext_vector_type(8)));
typedef float f32x4 __attribute__((ext_vector_type(4)));
typedef float f32x16 __attribute__((ext_vector_type(16)));
typedef unsigned short u16x8 __attribute__((ext_vector_type(8)));
typedef unsigned int u32x4 __attribute__((ext_vector_type(4)));

__device__ __forceinline__ unsigned short f2bf(float f) {
  unsigned u = __builtin_bit_cast(unsigned, f);
  u += 0x7fffu + ((u >> 16) & 1u);
  return (unsigned short)(u >> 16);
}

__device__ __forceinline__ void async16(const void* g, void* l) {
  __builtin_amdgcn_global_load_lds(
      (const __attribute__((address_space(1))) void*)(uintptr_t)g,
      (__attribute__((address_space(3))) void*)(unsigned)(uintptr_t)l,
      16, 0, 0);
}

__device__ __forceinline__ f32x4 mfma16(bf16x8 a, bf16x8 b, f32x4 c) {
  return __builtin_amdgcn_mfma_f32_16x16x32_bf16(a, b, c, 0, 0, 0);
}
__device__ __forceinline__ f32x16 mfma32(bf16x8 a, bf16x8 b, f32x16 c) {
  return __builtin_amdgcn_mfma_f32_32x32x16_bf16(a, b, c, 0, 0, 0);
}

__global__ __launch_bounds__(256) void cast_bf16_kernel(
    const float* __restrict__ in, unsigned short* __restrict__ out, int n8) {
  int i = blockIdx.x * 256 + threadIdx.x;
  if (i >= n8) return;
  size_t base = (size_t)i * 8;
  float4 a = *(const float4*)(in + base);
  float4 b = *(const float4*)(in + base + 4);
  u16x8 r;
  r[0] = f2bf(a.x); r[1] = f2bf(a.y); r[2] = f2bf(a.z); r[3] = f2bf(a.w);
  r[4] = f2bf(b.x); r[5] = f2bf(b.y); r[6] = f2bf(b.z); r[7] = f2bf(b.w);
  *(u16x8*)(out + base) = r;
}

// C = oscale * (A[M,K] @ W[N,K]^T)
// MODE 0: bf16 out, [B,H,S,Dh] layout   (Q, K projections)
// MODE 1: f32 out,  [M,N] row-major     (final output)
// MODE 2: bf16 out, [B,H,Dh,S] layout   (V projection, transposed)
// Grid is fixed at (8, M/128); XCD-swizzled internally (nwg % 8 == 0).
template <int MODE>
__global__ __launch_bounds__(256) void gemm_bt(
    const unsigned short* __restrict__ A, const unsigned short* __restrict__ W,
    void* __restrict__ out, float oscale, int M, int N, int K) {
  __shared__ __align__(16) unsigned short As[128 * 64];
  __shared__ __align__(16) unsigned short Bs[128 * 64];
  const int tid = threadIdx.x;
  const int lane = tid & 63;
  const int w = tid >> 6;
  const int wr = w >> 1, wc = w & 1;
  const int li = lane & 15, g = lane >> 4;

  // XCD-aware swizzle: 8 XCDs, nwg multiple of 8 -> bijective chunked remap.
  const int nwg = gridDim.x * gridDim.y;
  const int bid = blockIdx.y * gridDim.x + blockIdx.x;
  const int wg = (bid & 7) * (nwg >> 3) + (bid >> 3);
  const int bm = wg >> 3;          // gridDim.x == 8 always here
  const int bn = wg & 7;

  f32x4 acc[4][4];
  #pragma unroll
  for (int i = 0; i < 4; i++)
    #pragma unroll
    for (int j = 0; j < 4; j++)
      #pragma unroll
      for (int r = 0; r < 4; r++) acc[i][j][r] = 0.f;

  const int srow = w * 32 + (lane >> 3);
  const int scol = (lane & 7) * 8;

  for (int k0 = 0; k0 < K; k0 += 64) {
    #pragma unroll
    for (int p = 0; p < 4; ++p) {
      int r = srow + p * 8;
      async16(&A[(size_t)(bm * 128 + r) * K + k0 + scol], &As[(w * 32 + p * 8) * 64]);
      async16(&W[(size_t)(bn * 128 + r) * K + k0 + scol], &Bs[(w * 32 + p * 8) * 64]);
    }
    __syncthreads();
    #pragma unroll
    for (int kk = 0; kk < 2; ++kk) {
      bf16x8 a[4], b[4];
      #pragma unroll
      for (int i = 0; i < 4; i++)
        a[i] = *(const bf16x8*)&As[(wr * 64 + i * 16 + li) * 64 + kk * 32 + g * 8];
      #pragma unroll
      for (int j = 0; j < 4; j++)
        b[j] = *(const bf16x8*)&Bs[(wc * 64 + j * 16 + li) * 64 + kk * 32 + g * 8];
      #pragma unroll
      for (int i = 0; i < 4; i++)
        #pragma unroll
        for (int j = 0; j < 4; j++)
          acc[i][j] = mfma16(a[i], b[j], acc[i][j]);
    }
    __syncthreads();
  }

  #pragma unroll
  for (int i = 0; i < 4; i++)
    #pragma unroll
    for (int j = 0; j < 4; j++)
      #pragma unroll
      for (int r = 0; r < 4; r++) {
        int row = bm * 128 + wr * 64 + i * 16 + g * 4 + r;
        int col = bn * 128 + wc * 64 + j * 16 + li;
        float v = acc[i][j][r] * oscale;
        if constexpr (MODE == 0) {
          size_t idx = ((size_t)((row >> 11) * N_HEADS + (col >> 6)) * S_LEN +
                        (row & (S_LEN - 1))) * D_HEAD + (col & (D_HEAD - 1));
          ((unsigned short*)out)[idx] = f2bf(v);
        } else if constexpr (MODE == 1) {
          ((float*)out)[(size_t)row * N + col] = v;
        } else {
          size_t idx = ((size_t)((row >> 11) * N_HEADS + (col >> 6)) * D_HEAD +
                        (col & (D_HEAD - 1))) * S_LEN + (row & (S_LEN - 1));
          ((unsigned short*)out)[idx] = f2bf(v);
        }
      }
}

// Flash attention, swapped-operand 32x32 structure.
// grid (S/128, B*H), 256 thr = 4 waves; wave owns 32 q-rows.
// qh: [B,H,S,64] bf16, PRE-SCALED by 0.125*log2(e)  -> scores in exp2 domain.
// kh: [B,H,S,64] bf16. vt: [B,H,64,S] bf16. xout: [B,S,E] bf16.
// S^T = mfma32(K, Q): lane holds S[key=crow(r,hi)][q=lane&31].
// O^T = mfma32(V^T, P): lane holds O[d=crow(r,hi)+32*dt][q=lane&31].
__global__ __launch_bounds__(256) void attn_kernel(
    const unsigned short* __restrict__ qh, const unsigned short* __restrict__ kh,
    const unsigned short* __restrict__ vt, unsigned short* __restrict__ xout) {
  __shared__ float O_lds[4][32 * 65];
  const int lane = threadIdx.x & 63;
  const int w = threadIdx.x >> 6;
  const int l32 = lane & 31;
  const int hi = lane >> 5;
  const int bh = blockIdx.y;
  const int qb = blockIdx.x * 128 + w * 32;

  const unsigned short* Q = qh + (size_t)bh * S_LEN * D_HEAD;
  const unsigned short* Kp = kh + (size_t)bh * S_LEN * D_HEAD;
  const unsigned short* Vt = vt + (size_t)bh * D_HEAD * S_LEN;

  // Q B-frags: lane holds Q[qb+l32][d = ks*16 + hi*8 + j]
  bf16x8 qf[4];
  #pragma unroll
  for (int ks = 0; ks < 4; ks++)
    qf[ks] = *(const bf16x8*)&Q[(qb + l32) * 64 + ks * 16 + hi * 8];

  f32x16 o0, o1;
  #pragma unroll
  for (int r = 0; r < 16; r++) { o0[r] = 0.f; o1[r] = 0.f; }
  float m2 = -1e30f;   // running max (log2 domain)
  float lsum = 0.f;    // per-half partial sum; combined at epilogue

  // Prologue: K tile 0 fragments in registers.
  const unsigned short* K0 = &Kp[l32 * 64 + hi * 8];
  bf16x8 kf0 = *(const bf16x8*)&K0[0];
  bf16x8 kf1 = *(const bf16x8*)&K0[16];
  bf16x8 kf2 = *(const bf16x8*)&K0[32];
  bf16x8 kf3 = *(const bf16x8*)&K0[48];

  #pragma unroll 2
  for (int kv = 0; kv < S_LEN; kv += 32) {
    // V loads issued early: latency hides under QK + softmax.
    const unsigned short* Vb = Vt + kv + hi * 8;
    bf16x8 v00 = *(const bf16x8*)&Vb[(size_t)l32 * S_LEN];
    bf16x8 v01 = *(const bf16x8*)&Vb[(size_t)l32 * S_LEN + 16];
    bf16x8 v10 = *(const bf16x8*)&Vb[(size_t)(32 + l32) * S_LEN];
    bf16x8 v11 = *(const bf16x8*)&Vb[(size_t)(32 + l32) * S_LEN + 16];

    f32x16 s;
    #pragma unroll
    for (int r = 0; r < 16; r++) s[r] = 0.f;
    __builtin_amdgcn_s_setprio(1);
    s = mfma32(kf0, qf[0], s);
    s = mfma32(kf1, qf[1], s);
    s = mfma32(kf2, qf[2], s);
    s = mfma32(kf3, qf[3], s);
    __builtin_amdgcn_s_setprio(0);

    // Prefetch next K tile (register double-buffer).
    int kn = (kv + 32 < S_LEN) ? kv + 32 : 0;
    const unsigned short* Kn = &Kp[(kn + l32) * 64 + hi * 8];
    bf16x8 n0 = *(const bf16x8*)&Kn[0];
    bf16x8 n1 = *(const bf16x8*)&Kn[16];
    bf16x8 n2 = *(const bf16x8*)&Kn[32];
    bf16x8 n3 = *(const bf16x8*)&Kn[48];

    // s[r] is already in log2 domain (Q pre-scaled). Online softmax w/ defer-max.
    float mx = fmaxf(s[0], s[1]);
    #pragma unroll
    for (int r = 2; r < 16; r++) mx = fmaxf(mx, s[r]);
    mx = fmaxf(mx, __shfl_xor(mx, 32));
    if (__any(mx > m2 + 8.0f)) {        // rare after first tile
      float mn = fmaxf(m2, mx);
      float sc = __builtin_amdgcn_exp2f(m2 - mn);
      lsum *= sc;
      #pragma unroll
      for (int r = 0; r < 16; r++) { o0[r] *= sc; o1[r] *= sc; }
      m2 = mn;
    }
    float p[16];
    float ts = 0.f;
    #pragma unroll
    for (int r = 0; r < 16; r++) {
      p[r] = __builtin_amdgcn_exp2f(s[r] - m2);   // bounded by 2^8
      ts += p[r];
    }
    lsum += ts;

    // P -> bf16 A-frag layout via cvt_pk + permlane32_swap.
    unsigned c[8];
    #pragma unroll
    for (int t = 0; t < 8; t++)
      asm("v_cvt_pk_bf16_f32 %0, %1, %2"
          : "=v"(c[t]) : "v"(p[2 * t]), "v"(p[2 * t + 1]));
    asm("v_permlane32_swap_b32 %0, %1" : "+v"(c[0]), "+v"(c[2]));
    asm("v_permlane32_swap_b32 %0, %1" : "+v"(c[1]), "+v"(c[3]));
    asm("v_permlane32_swap_b32 %0, %1" : "+v"(c[4]), "+v"(c[6]));
    asm("v_permlane32_swap_b32 %0, %1" : "+v"(c[5]), "+v"(c[7]));
    u32x4 t0 = {c[0], c[1], c[2], c[3]};
    u32x4 t1 = {c[4], c[5], c[6], c[7]};
    bf16x8 pa0 = __builtin_bit_cast(bf16x8, t0);
    bf16x8 pa1 = __builtin_bit_cast(bf16x8, t1);

    __builtin_amdgcn_s_setprio(1);
    o0 = mfma32(v00, pa0, o0);
    o0 = mfma32(v01, pa1, o0);
    o1 = mfma32(v10, pa0, o1);
    o1 = mfma32(v11, pa1, o1);
    __builtin_amdgcn_s_setprio(0);

    kf0 = n0; kf1 = n1; kf2 = n2; kf3 = n3;
  }

  lsum += __shfl_xor(lsum, 32);

  // Epilogue: normalize, transpose O^T -> O via padded LDS, coalesced store.
  float inv = 1.0f / lsum;
  #pragma unroll
  for (int r = 0; r < 16; r++) {
    int d = (r & 3) + 8 * (r >> 2) + 4 * hi;
    O_lds[w][l32 * 65 + d] = o0[r] * inv;
    O_lds[w][l32 * 65 + 32 + d] = o1[r] * inv;
  }
  const int qr = lane >> 1;
  const int coff = (lane & 1) * 32;
  const int b = bh >> 4, h = bh & 15;
  unsigned short* dst =
      &xout[((size_t)(b * S_LEN) + qb + qr) * D_EMBD + h * 64 + coff];
  #pragma unroll
  for (int t = 0; t < 4; t++) {
    u16x8 rr;
    #pragma unroll
    for (int j = 0; j < 8; j++)
      rr[j] = f2bf(O_lds[w][qr * 65 + coff + t * 8 + j]);
    *(u16x8*)(dst + t * 8) = rr;
  }
}

extern "C" void kernel_launch(void* const* d_in, const int* in_sizes, int n_in,
                              void* d_out, int out_size, void* d_ws, size_t ws_size,
                              hipStream_t stream) {
  const float* q   = (const float*)d_in[0];
  const float* k   = (const float*)d_in[1];
  const float* v   = (const float*)d_in[2];
  const float* wqf = (const float*)d_in[3];
  const float* wkf = (const float*)d_in[4];
  const float* wvf = (const float*)d_in[5];
  const float* wof = (const float*)d_in[6];

  char* ws = (char*)d_ws;
  unsigned short* castbuf = (unsigned short*)(ws);                 // 16 MB
  unsigned short* qh = (unsigned short*)(ws + (16u << 20));        // 16 MB
  unsigned short* kh = (unsigned short*)(ws + (32u << 20));        // 16 MB
  unsigned short* vt = (unsigned short*)(ws + (48u << 20));        // 16 MB
  unsigned short* ax = (unsigned short*)(ws + (64u << 20));        // 16 MB
  unsigned short* wq = (unsigned short*)(ws + (80u << 20));        // 2 MB
  unsigned short* wk = wq + (1u << 20);
  unsigned short* wv = wk + (1u << 20);
  unsigned short* wo = wv + (1u << 20);

  const int MK8 = M_TOT * D_EMBD / 8;   // 1048576
  const int WK8 = D_EMBD * D_EMBD / 8;  // 131072

  // 0.125 (=1/sqrt(Dh)) * log2(e): puts QK^T scores directly in exp2 domain.
  const float QSCALE = 0.125f * 1.4426950408889634f;

  cast_bf16_kernel<<<WK8 / 256, 256, 0, stream>>>(wqf, wq, WK8);
  cast_bf16_kernel<<<WK8 / 256, 256, 0, stream>>>(wkf, wk, WK8);
  cast_bf16_kernel<<<WK8 / 256, 256, 0, stream>>>(wvf, wv, WK8);
  cast_bf16_kernel<<<WK8 / 256, 256, 0, stream>>>(wof, wo, WK8);

  dim3 gg(D_EMBD / 128, M_TOT / 128);  // (8, 64)

  cast_bf16_kernel<<<MK8 / 256, 256, 0, stream>>>(q, castbuf, MK8);
  gemm_bt<0><<<gg, 256, 0, stream>>>(castbuf, wq, qh, QSCALE, M_TOT, D_EMBD, D_EMBD);
  cast_bf16_kernel<<<MK8 / 256, 256, 0, stream>>>(k, castbuf, MK8);
  gemm_bt<0><<<gg, 256, 0, stream>>>(castbuf, wk, kh, 1.0f, M_TOT, D_EMBD, D_EMBD);
  cast_bf16_kernel<<<MK8 / 256, 256, 0, stream>>>(v, castbuf, MK8);
  gemm_bt<2><<<gg, 256, 0, stream>>>(castbuf, wv, vt, 1.0f, M_TOT, D_EMBD, D_EMBD);

  attn_kernel<<<dim3(S_LEN / 128, B_SZ * N_HEADS), 256, 0, stream>>>(qh, kh, vt, ax);

  gemm_bt<1><<<gg, 256, 0, stream>>>(ax, wo, d_out, 1.0f, M_TOT, D_EMBD, D_EMBD);
}

// Round 4
// 254.719 us; speedup vs baseline: 1.5302x; 1.5302x over previous
//
#include <hip/hip_runtime.h>
#include <stdint.h>

#define S_LEN 2048
#define D_EMBD 1024
#define N_HEADS 16
#define D_HEAD 64
#define B_SZ 4
#define M_TOT (B_SZ * S_LEN)   // 8192

typedef __bf16 bf16x8 __attribute__((ext_vector_type(8)));
typedef float f32x4 __attribute__((ext_vector_type(4)));
typedef float f32x16 __attribute__((ext_vector_type(16)));
typedef unsigned short u16x8 __attribute__((ext_vector_type(8)));
typedef unsigned int u32x4 __attribute__((ext_vector_type(4)));

__device__ __forceinline__ unsigned short f2bf(float f) {
  unsigned u = __builtin_bit_cast(unsigned, f);
  u += 0x7fffu + ((u >> 16) & 1u);
  return (unsigned short)(u >> 16);
}

__device__ __forceinline__ void async16(const void* g, void* l) {
  __builtin_amdgcn_global_load_lds(
      (const __attribute__((address_space(1))) void*)(uintptr_t)g,
      (__attribute__((address_space(3))) void*)(unsigned)(uintptr_t)l,
      16, 0, 0);
}

__device__ __forceinline__ f32x4 mfma16(bf16x8 a, bf16x8 b, f32x4 c) {
  return __builtin_amdgcn_mfma_f32_16x16x32_bf16(a, b, c, 0, 0, 0);
}
__device__ __forceinline__ f32x16 mfma32(bf16x8 a, bf16x8 b, f32x16 c) {
  return __builtin_amdgcn_mfma_f32_32x32x16_bf16(a, b, c, 0, 0, 0);
}

__global__ __launch_bounds__(256) void cast_bf16_kernel(
    const float* __restrict__ in, unsigned short* __restrict__ out, int n8) {
  int i = blockIdx.x * 256 + threadIdx.x;
  if (i >= n8) return;
  size_t base = (size_t)i * 8;
  float4 a = *(const float4*)(in + base);
  float4 b = *(const float4*)(in + base + 4);
  u16x8 r;
  r[0] = f2bf(a.x); r[1] = f2bf(a.y); r[2] = f2bf(a.z); r[3] = f2bf(a.w);
  r[4] = f2bf(b.x); r[5] = f2bf(b.y); r[6] = f2bf(b.z); r[7] = f2bf(b.w);
  *(u16x8*)(out + base) = r;
}

// C = oscale * (A[M,K] @ W[N,K]^T)
// MODE 0: bf16 out, [B,H,S,Dh] layout   (Q, K projections)
// MODE 1: f32 out,  [M,N] row-major     (final output)
// MODE 2: bf16 out, [B,H,Dh,S] layout   (V projection, transposed)
template <int MODE>
__global__ __launch_bounds__(256) void gemm_bt(
    const unsigned short* __restrict__ A, const unsigned short* __restrict__ W,
    void* __restrict__ out, float oscale, int M, int N, int K) {
  __shared__ __align__(16) unsigned short As[128 * 64];
  __shared__ __align__(16) unsigned short Bs[128 * 64];
  const int tid = threadIdx.x;
  const int lane = tid & 63;
  const int w = tid >> 6;
  const int wr = w >> 1, wc = w & 1;
  const int li = lane & 15, g = lane >> 4;

  const int nwg = gridDim.x * gridDim.y;
  const int bid = blockIdx.y * gridDim.x + blockIdx.x;
  const int wg = (bid & 7) * (nwg >> 3) + (bid >> 3);
  const int bm = wg >> 3;
  const int bn = wg & 7;

  f32x4 acc[4][4];
  #pragma unroll
  for (int i = 0; i < 4; i++)
    #pragma unroll
    for (int j = 0; j < 4; j++)
      #pragma unroll
      for (int r = 0; r < 4; r++) acc[i][j][r] = 0.f;

  const int srow = w * 32 + (lane >> 3);
  const int scol = (lane & 7) * 8;

  for (int k0 = 0; k0 < K; k0 += 64) {
    #pragma unroll
    for (int p = 0; p < 4; ++p) {
      int r = srow + p * 8;
      async16(&A[(size_t)(bm * 128 + r) * K + k0 + scol], &As[(w * 32 + p * 8) * 64]);
      async16(&W[(size_t)(bn * 128 + r) * K + k0 + scol], &Bs[(w * 32 + p * 8) * 64]);
    }
    __syncthreads();
    #pragma unroll
    for (int kk = 0; kk < 2; ++kk) {
      bf16x8 a[4], b[4];
      #pragma unroll
      for (int i = 0; i < 4; i++)
        a[i] = *(const bf16x8*)&As[(wr * 64 + i * 16 + li) * 64 + kk * 32 + g * 8];
      #pragma unroll
      for (int j = 0; j < 4; j++)
        b[j] = *(const bf16x8*)&Bs[(wc * 64 + j * 16 + li) * 64 + kk * 32 + g * 8];
      #pragma unroll
      for (int i = 0; i < 4; i++)
        #pragma unroll
        for (int j = 0; j < 4; j++)
          acc[i][j] = mfma16(a[i], b[j], acc[i][j]);
    }
    __syncthreads();
  }

  #pragma unroll
  for (int i = 0; i < 4; i++)
    #pragma unroll
    for (int j = 0; j < 4; j++)
      #pragma unroll
      for (int r = 0; r < 4; r++) {
        int row = bm * 128 + wr * 64 + i * 16 + g * 4 + r;
        int col = bn * 128 + wc * 64 + j * 16 + li;
        float v = acc[i][j][r] * oscale;
        if constexpr (MODE == 0) {
          size_t idx = ((size_t)((row >> 11) * N_HEADS + (col >> 6)) * S_LEN +
                        (row & (S_LEN - 1))) * D_HEAD + (col & (D_HEAD - 1));
          ((unsigned short*)out)[idx] = f2bf(v);
        } else if constexpr (MODE == 1) {
          ((float*)out)[(size_t)row * N + col] = v;
        } else {
          size_t idx = ((size_t)((row >> 11) * N_HEADS + (col >> 6)) * D_HEAD +
                        (col & (D_HEAD - 1))) * S_LEN + (row & (S_LEN - 1));
          ((unsigned short*)out)[idx] = f2bf(v);
        }
      }
}

// Flash attention, swapped-operand 32x32, LDS-staged K/V shared by 4 waves.
// 1D grid 1024 blocks (XCD-swizzled: head-major so each XCD owns 8 heads).
// qh: [B,H,S,64] bf16 PRE-SCALED by 0.125*log2(e). kh: [B,H,S,64]. vt: [B,H,64,S].
// LDS (33280 B): K tiles @ {0, 8192}, V tiles @ {16384, 24576}; each tile
// 64 rows x 128 B, element swizzle byte ^= ((row&7)<<4). Reused as O_lds at epilogue.
__global__ __launch_bounds__(256, 4) void attn_kernel(
    const unsigned short* __restrict__ qh, const unsigned short* __restrict__ kh,
    const unsigned short* __restrict__ vt, unsigned short* __restrict__ xout) {
  __shared__ __align__(16) char smem[33280];
  const int lane = threadIdx.x & 63;
  const int w = threadIdx.x >> 6;
  const int l32 = lane & 31;
  const int hi = lane >> 5;

  const int bid = blockIdx.x;                    // nwg = 1024
  const int wg = (bid & 7) * 128 + (bid >> 3);   // XCD-chunked remap
  const int bh = wg >> 4;
  const int qb = (wg & 15) * 128 + w * 32;

  const char* Kb = (const char*)kh + (size_t)bh * S_LEN * D_HEAD * 2;
  const char* Vb = (const char*)vt + (size_t)bh * D_HEAD * S_LEN * 2;
  const unsigned short* Q = qh + (size_t)bh * S_LEN * D_HEAD;

  // Q B-frags: lane holds Q[qb+l32][ks*16 + hi*8 + j]
  bf16x8 qf[4];
  #pragma unroll
  for (int ks = 0; ks < 4; ks++)
    qf[ks] = *(const bf16x8*)&Q[(qb + l32) * 64 + ks * 16 + hi * 8];

  f32x16 o0, o1;
  #pragma unroll
  for (int r = 0; r < 16; r++) { o0[r] = 0.f; o1[r] = 0.f; }
  float m2 = -1e30f;
  float lsum = 0.f;

  // --- staging: K tile (8KB contiguous) + V tile (64 rows x 128B, stride 4KB),
  // linear LDS dest, inverse-swizzled global source (rule #21).
  #define STAGE(bufi, kv)                                                      \
    do {                                                                       \
      _Pragma("unroll")                                                        \
      for (int p = 0; p < 2; p++) {                                            \
        int loff = (w * 2 + p) * 1024 + lane * 16;                             \
        int krow = loff >> 7;                                                  \
        async16(Kb + (kv) * 128 + (loff ^ ((krow & 7) << 4)),                  \
                smem + (bufi) * 8192 + (w * 2 + p) * 1024);                    \
      }                                                                        \
      _Pragma("unroll")                                                        \
      for (int p = 0; p < 2; p++) {                                            \
        int loff = (w * 2 + p) * 1024 + lane * 16;                             \
        int d = loff >> 7;                                                     \
        int colb = loff & 127;                                                 \
        async16(Vb + (size_t)d * (S_LEN * 2) + (kv) * 2 +                      \
                    (colb ^ ((d & 7) << 4)),                                   \
                smem + 16384 + (bufi) * 8192 + (w * 2 + p) * 1024);            \
      }                                                                        \
    } while (0)

  STAGE(0, 0);
  __syncthreads();

  int buf = 0;
  for (int it = 0; it < S_LEN / 64; it++) {
    if (it < S_LEN / 64 - 1) STAGE(buf ^ 1, (it + 1) * 64);

    const char* Ks = smem + buf * 8192;
    const char* Vs = smem + 16384 + buf * 8192;

    f32x16 s0, s1;
    #pragma unroll
    for (int r = 0; r < 16; r++) { s0[r] = 0.f; s1[r] = 0.f; }

    __builtin_amdgcn_s_setprio(1);
    #pragma unroll
    for (int ks = 0; ks < 4; ks++) {
      int row = l32;
      bf16x8 ka = *(const bf16x8*)(Ks + ((row * 128 + ks * 32 + hi * 16) ^
                                         ((row & 7) << 4)));
      s0 = mfma32(ka, qf[ks], s0);
    }
    #pragma unroll
    for (int ks = 0; ks < 4; ks++) {
      int row = 32 + l32;
      bf16x8 ka = *(const bf16x8*)(Ks + ((row * 128 + ks * 32 + hi * 16) ^
                                         ((row & 7) << 4)));
      s1 = mfma32(ka, qf[ks], s1);
    }
    __builtin_amdgcn_s_setprio(0);

    // online softmax (log2 domain; Q pre-scaled), defer-max THR=8
    float mx = fmaxf(s0[0], s0[1]);
    #pragma unroll
    for (int r = 2; r < 16; r++) mx = fmaxf(mx, s0[r]);
    #pragma unroll
    for (int r = 0; r < 16; r++) mx = fmaxf(mx, s1[r]);
    mx = fmaxf(mx, __shfl_xor(mx, 32));
    if (__any(mx > m2 + 8.0f)) {
      float mn = fmaxf(m2, mx);
      float sc = __builtin_amdgcn_exp2f(m2 - mn);
      lsum *= sc;
      #pragma unroll
      for (int r = 0; r < 16; r++) { o0[r] *= sc; o1[r] *= sc; }
      m2 = mn;
    }
    float ts = 0.f;
    #pragma unroll
    for (int r = 0; r < 16; r++) {
      s0[r] = __builtin_amdgcn_exp2f(s0[r] - m2);
      s1[r] = __builtin_amdgcn_exp2f(s1[r] - m2);
      ts += s0[r] + s1[r];
    }
    lsum += ts;

    // P -> bf16 A-frags (keys 0..63) via cvt_pk + permlane32_swap
    unsigned c[8], e[8];
    #pragma unroll
    for (int t = 0; t < 8; t++) {
      asm("v_cvt_pk_bf16_f32 %0, %1, %2"
          : "=v"(c[t]) : "v"(s0[2 * t]), "v"(s0[2 * t + 1]));
      asm("v_cvt_pk_bf16_f32 %0, %1, %2"
          : "=v"(e[t]) : "v"(s1[2 * t]), "v"(s1[2 * t + 1]));
    }
    asm("v_permlane32_swap_b32 %0, %1" : "+v"(c[0]), "+v"(c[2]));
    asm("v_permlane32_swap_b32 %0, %1" : "+v"(c[1]), "+v"(c[3]));
    asm("v_permlane32_swap_b32 %0, %1" : "+v"(c[4]), "+v"(c[6]));
    asm("v_permlane32_swap_b32 %0, %1" : "+v"(c[5]), "+v"(c[7]));
    asm("v_permlane32_swap_b32 %0, %1" : "+v"(e[0]), "+v"(e[2]));
    asm("v_permlane32_swap_b32 %0, %1" : "+v"(e[1]), "+v"(e[3]));
    asm("v_permlane32_swap_b32 %0, %1" : "+v"(e[4]), "+v"(e[6]));
    asm("v_permlane32_swap_b32 %0, %1" : "+v"(e[5]), "+v"(e[7]));
    u32x4 t0 = {c[0], c[1], c[2], c[3]};
    u32x4 t1 = {c[4], c[5], c[6], c[7]};
    u32x4 t2 = {e[0], e[1], e[2], e[3]};
    u32x4 t3 = {e[4], e[5], e[6], e[7]};
    bf16x8 pa0 = __builtin_bit_cast(bf16x8, t0);
    bf16x8 pa1 = __builtin_bit_cast(bf16x8, t1);
    bf16x8 pa2 = __builtin_bit_cast(bf16x8, t2);
    bf16x8 pa3 = __builtin_bit_cast(bf16x8, t3);

    __builtin_amdgcn_s_setprio(1);
    {
      int row = l32;
      bf16x8 va0 = *(const bf16x8*)(Vs + ((row * 128 + 0 * 32 + hi * 16) ^ ((row & 7) << 4)));
      bf16x8 va1 = *(const bf16x8*)(Vs + ((row * 128 + 1 * 32 + hi * 16) ^ ((row & 7) << 4)));
      bf16x8 va2 = *(const bf16x8*)(Vs + ((row * 128 + 2 * 32 + hi * 16) ^ ((row & 7) << 4)));
      bf16x8 va3 = *(const bf16x8*)(Vs + ((row * 128 + 3 * 32 + hi * 16) ^ ((row & 7) << 4)));
      o0 = mfma32(va0, pa0, o0);
      o0 = mfma32(va1, pa1, o0);
      o0 = mfma32(va2, pa2, o0);
      o0 = mfma32(va3, pa3, o0);
    }
    {
      int row = 32 + l32;
      bf16x8 va0 = *(const bf16x8*)(Vs + ((row * 128 + 0 * 32 + hi * 16) ^ ((row & 7) << 4)));
      bf16x8 va1 = *(const bf16x8*)(Vs + ((row * 128 + 1 * 32 + hi * 16) ^ ((row & 7) << 4)));
      bf16x8 va2 = *(const bf16x8*)(Vs + ((row * 128 + 2 * 32 + hi * 16) ^ ((row & 7) << 4)));
      bf16x8 va3 = *(const bf16x8*)(Vs + ((row * 128 + 3 * 32 + hi * 16) ^ ((row & 7) << 4)));
      o1 = mfma32(va0, pa0, o1);
      o1 = mfma32(va1, pa1, o1);
      o1 = mfma32(va2, pa2, o1);
      o1 = mfma32(va3, pa3, o1);
    }
    __builtin_amdgcn_s_setprio(0);

    __syncthreads();   // drains stage vmcnt; all waves done reading buf
    buf ^= 1;
  }
  #undef STAGE

  lsum += __shfl_xor(lsum, 32);
  float inv = 1.0f / lsum;

  // Epilogue: transpose O^T -> O via padded LDS (reuse smem), coalesced store.
  float* O = (float*)smem + w * (32 * 65);
  #pragma unroll
  for (int r = 0; r < 16; r++) {
    int d = (r & 3) + 8 * (r >> 2) + 4 * hi;
    O[l32 * 65 + d] = o0[r] * inv;
    O[l32 * 65 + 32 + d] = o1[r] * inv;
  }
  __builtin_amdgcn_s_barrier();  // wave-local region, but cheap; orders ds ops
  const int qr = lane >> 1;
  const int coff = (lane & 1) * 32;
  const int b = bh >> 4, h = bh & 15;
  unsigned short* dst =
      &xout[((size_t)(b * S_LEN) + qb + qr) * D_EMBD + h * 64 + coff];
  #pragma unroll
  for (int t = 0; t < 4; t++) {
    u16x8 rr;
    #pragma unroll
    for (int j = 0; j < 8; j++)
      rr[j] = f2bf(O[qr * 65 + coff + t * 8 + j]);
    *(u16x8*)(dst + t * 8) = rr;
  }
}

extern "C" void kernel_launch(void* const* d_in, const int* in_sizes, int n_in,
                              void* d_out, int out_size, void* d_ws, size_t ws_size,
                              hipStream_t stream) {
  const float* q   = (const float*)d_in[0];
  const float* k   = (const float*)d_in[1];
  const float* v   = (const float*)d_in[2];
  const float* wqf = (const float*)d_in[3];
  const float* wkf = (const float*)d_in[4];
  const float* wvf = (const float*)d_in[5];
  const float* wof = (const float*)d_in[6];

  char* ws = (char*)d_ws;
  unsigned short* castbuf = (unsigned short*)(ws);                 // 16 MB
  unsigned short* qh = (unsigned short*)(ws + (16u << 20));        // 16 MB
  unsigned short* kh = (unsigned short*)(ws + (32u << 20));        // 16 MB
  unsigned short* vt = (unsigned short*)(ws + (48u << 20));        // 16 MB
  unsigned short* ax = (unsigned short*)(ws + (64u << 20));        // 16 MB
  unsigned short* wq = (unsigned short*)(ws + (80u << 20));        // 2 MB
  unsigned short* wk = wq + (1u << 20);
  unsigned short* wv = wk + (1u << 20);
  unsigned short* wo = wv + (1u << 20);

  const int MK8 = M_TOT * D_EMBD / 8;   // 1048576
  const int WK8 = D_EMBD * D_EMBD / 8;  // 131072

  const float QSCALE = 0.125f * 1.4426950408889634f;

  cast_bf16_kernel<<<WK8 / 256, 256, 0, stream>>>(wqf, wq, WK8);
  cast_bf16_kernel<<<WK8 / 256, 256, 0, stream>>>(wkf, wk, WK8);
  cast_bf16_kernel<<<WK8 / 256, 256, 0, stream>>>(wvf, wv, WK8);
  cast_bf16_kernel<<<WK8 / 256, 256, 0, stream>>>(wof, wo, WK8);

  dim3 gg(D_EMBD / 128, M_TOT / 128);  // (8, 64)

  cast_bf16_kernel<<<MK8 / 256, 256, 0, stream>>>(q, castbuf, MK8);
  gemm_bt<0><<<gg, 256, 0, stream>>>(castbuf, wq, qh, QSCALE, M_TOT, D_EMBD, D_EMBD);
  cast_bf16_kernel<<<MK8 / 256, 256, 0, stream>>>(k, castbuf, MK8);
  gemm_bt<0><<<gg, 256, 0, stream>>>(castbuf, wk, kh, 1.0f, M_TOT, D_EMBD, D_EMBD);
  cast_bf16_kernel<<<MK8 / 256, 256, 0, stream>>>(v, castbuf, MK8);
  gemm_bt<2><<<gg, 256, 0, stream>>>(castbuf, wv, vt, 1.0f, M_TOT, D_EMBD, D_EMBD);

  attn_kernel<<<1024, 256, 0, stream>>>(qh, kh, vt, ax);

  gemm_bt<1><<<gg, 256, 0, stream>>>(ax, wo, d_out, 1.0f, M_TOT, D_EMBD, D_EMBD);
}

// Round 5
// 234.584 us; speedup vs baseline: 1.6616x; 1.0858x over previous
//
#include <hip/hip_runtime.h>
#include <stdint.h>

#define S_LEN 2048
#define D_EMBD 1024
#define N_HEADS 16
#define D_HEAD 64
#define B_SZ 4
#define M_TOT (B_SZ * S_LEN)   // 8192

typedef __bf16 bf16x8 __attribute__((ext_vector_type(8)));
typedef float f32x4 __attribute__((ext_vector_type(4)));
typedef float f32x16 __attribute__((ext_vector_type(16)));
typedef unsigned short u16x8 __attribute__((ext_vector_type(8)));
typedef unsigned int u32x4 __attribute__((ext_vector_type(4)));

__device__ __forceinline__ unsigned short f2bf(float f) {
  unsigned u = __builtin_bit_cast(unsigned, f);
  u += 0x7fffu + ((u >> 16) & 1u);
  return (unsigned short)(u >> 16);
}

__device__ __forceinline__ void async16(const void* g, void* l) {
  __builtin_amdgcn_global_load_lds(
      (const __attribute__((address_space(1))) void*)(uintptr_t)g,
      (__attribute__((address_space(3))) void*)(unsigned)(uintptr_t)l,
      16, 0, 0);
}

__device__ __forceinline__ f32x16 mfma32(bf16x8 a, bf16x8 b, f32x16 c) {
  return __builtin_amdgcn_mfma_f32_32x32x16_bf16(a, b, c, 0, 0, 0);
}

__global__ __launch_bounds__(256) void cast_bf16_kernel(
    const float* __restrict__ in, unsigned short* __restrict__ out, int n8) {
  int i = blockIdx.x * 256 + threadIdx.x;
  if (i >= n8) return;
  size_t base = (size_t)i * 8;
  float4 a = *(const float4*)(in + base);
  float4 b = *(const float4*)(in + base + 4);
  u16x8 r;
  r[0] = f2bf(a.x); r[1] = f2bf(a.y); r[2] = f2bf(a.z); r[3] = f2bf(a.w);
  r[4] = f2bf(b.x); r[5] = f2bf(b.y); r[6] = f2bf(b.z); r[7] = f2bf(b.w);
  *(u16x8*)(out + base) = r;
}

// All 4 weight matrices cast in one launch; dst buffers are contiguous.
__global__ __launch_bounds__(256) void cast_w4_kernel(
    const float* __restrict__ w0, const float* __restrict__ w1,
    const float* __restrict__ w2, const float* __restrict__ w3,
    unsigned short* __restrict__ out) {
  int i = blockIdx.x * 256 + threadIdx.x;        // 4 * 131072 threads
  int seg = i >> 17;
  int off = i & ((1 << 17) - 1);
  const float* src = (seg == 0) ? w0 : (seg == 1) ? w1 : (seg == 2) ? w2 : w3;
  size_t sb = (size_t)off * 8;
  float4 a = *(const float4*)(src + sb);
  float4 b = *(const float4*)(src + sb + 4);
  u16x8 r;
  r[0] = f2bf(a.x); r[1] = f2bf(a.y); r[2] = f2bf(a.z); r[3] = f2bf(a.w);
  r[4] = f2bf(b.x); r[5] = f2bf(b.y); r[6] = f2bf(b.z); r[7] = f2bf(b.w);
  *(u16x8*)(out + (size_t)i * 8) = r;
}

// C = oscale * (A[M,K] @ W[N,K]^T), 32x32x16 MFMA, XOR-swizzled LDS.
// MODE 0: bf16 out, [B,H,S,Dh]; MODE 1: f32 out [M,N]; MODE 2: bf16 [B,H,Dh,S].
template <int MODE>
__global__ __launch_bounds__(256) void gemm_bt(
    const unsigned short* __restrict__ A, const unsigned short* __restrict__ W,
    void* __restrict__ out, float oscale, int M, int N, int K) {
  __shared__ __align__(16) unsigned short As[128 * 64];
  __shared__ __align__(16) unsigned short Bs[128 * 64];
  const int tid = threadIdx.x;
  const int lane = tid & 63;
  const int w = tid >> 6;
  const int wr = w >> 1, wc = w & 1;
  const int l32 = lane & 31, hi = lane >> 5;

  const int nwg = gridDim.x * gridDim.y;
  const int bid = blockIdx.y * gridDim.x + blockIdx.x;
  const int wg = (bid & 7) * (nwg >> 3) + (bid >> 3);
  const int bm = wg >> 3;
  const int bn = wg & 7;

  f32x16 acc[2][2];
  #pragma unroll
  for (int i = 0; i < 2; i++)
    #pragma unroll
    for (int j = 0; j < 2; j++)
      #pragma unroll
      for (int r = 0; r < 16; r++) acc[i][j][r] = 0.f;

  // Staging: LDS[row][c] = Global[row][c ^ (row&7)] (16B chunks). Linear LDS
  // dest (gload_lds requirement), inverse-swizzled global source.
  const int srow = w * 32 + (lane >> 3);
  const int scolsw = ((lane & 7) ^ (lane >> 3)) * 8;   // elems

  for (int k0 = 0; k0 < K; k0 += 64) {
    #pragma unroll
    for (int p = 0; p < 4; ++p) {
      async16(&A[(size_t)(bm * 128 + srow + p * 8) * K + k0 + scolsw],
              &As[(w * 32 + p * 8) * 64]);
      async16(&W[(size_t)(bn * 128 + srow + p * 8) * K + k0 + scolsw],
              &Bs[(w * 32 + p * 8) * 64]);
    }
    __syncthreads();
    #pragma unroll
    for (int ksub = 0; ksub < 4; ++ksub) {
      const int koff = ksub * 32 + hi * 16;   // byte offset in 128B row
      bf16x8 aA[2], bB[2];
      #pragma unroll
      for (int rb = 0; rb < 2; rb++) {
        int row = wr * 64 + rb * 32 + l32;
        aA[rb] = *(const bf16x8*)((const char*)As + row * 128 +
                                  (koff ^ ((l32 & 7) << 4)));
      }
      #pragma unroll
      for (int cb = 0; cb < 2; cb++) {
        int row = wc * 64 + cb * 32 + l32;
        bB[cb] = *(const bf16x8*)((const char*)Bs + row * 128 +
                                  (koff ^ ((l32 & 7) << 4)));
      }
      #pragma unroll
      for (int rb = 0; rb < 2; rb++)
        #pragma unroll
        for (int cb = 0; cb < 2; cb++)
          acc[rb][cb] = mfma32(aA[rb], bB[cb], acc[rb][cb]);
    }
    __syncthreads();
  }

  // 32x32 C/D layout: col = l32, row = (r&3) + 8*(r>>2) + 4*hi.
  #pragma unroll
  for (int rb = 0; rb < 2; rb++)
    #pragma unroll
    for (int cb = 0; cb < 2; cb++)
      #pragma unroll
      for (int r = 0; r < 16; r++) {
        int row = bm * 128 + wr * 64 + rb * 32 + (r & 3) + 8 * (r >> 2) + 4 * hi;
        int col = bn * 128 + wc * 64 + cb * 32 + l32;
        float v = acc[rb][cb][r] * oscale;
        if constexpr (MODE == 0) {
          size_t idx = ((size_t)((row >> 11) * N_HEADS + (col >> 6)) * S_LEN +
                        (row & (S_LEN - 1))) * D_HEAD + (col & (D_HEAD - 1));
          ((unsigned short*)out)[idx] = f2bf(v);
        } else if constexpr (MODE == 1) {
          ((float*)out)[(size_t)row * N + col] = v;
        } else {
          size_t idx = ((size_t)((row >> 11) * N_HEADS + (col >> 6)) * D_HEAD +
                        (col & (D_HEAD - 1))) * S_LEN + (row & (S_LEN - 1));
          ((unsigned short*)out)[idx] = f2bf(v);
        }
      }
}

// Flash attention, swapped-operand 32x32, LDS-staged K/V shared by 4 waves.
// Row-sum of P via mfma32(ones, pa) -> lacc (frees ~32 VALU adds/tile and the
// cross-half shuffle: the matrix dot sums both hi-halves internally).
__global__ __launch_bounds__(256, 4) void attn_kernel(
    const unsigned short* __restrict__ qh, const unsigned short* __restrict__ kh,
    const unsigned short* __restrict__ vt, unsigned short* __restrict__ xout) {
  __shared__ __align__(16) char smem[33280];
  const int lane = threadIdx.x & 63;
  const int w = threadIdx.x >> 6;
  const int l32 = lane & 31;
  const int hi = lane >> 5;

  const int bid = blockIdx.x;                    // nwg = 1024
  const int wg = (bid & 7) * 128 + (bid >> 3);   // XCD-chunked remap
  const int bh = wg >> 4;
  const int qb = (wg & 15) * 128 + w * 32;

  const char* Kb = (const char*)kh + (size_t)bh * S_LEN * D_HEAD * 2;
  const char* Vb = (const char*)vt + (size_t)bh * D_HEAD * S_LEN * 2;
  const unsigned short* Q = qh + (size_t)bh * S_LEN * D_HEAD;

  bf16x8 qf[4];
  #pragma unroll
  for (int ks = 0; ks < 4; ks++)
    qf[ks] = *(const bf16x8*)&Q[(qb + l32) * 64 + ks * 16 + hi * 8];

  u16x8 ou;
  #pragma unroll
  for (int j = 0; j < 8; j++) ou[j] = 0x3F80;   // bf16 1.0
  const bf16x8 ones = __builtin_bit_cast(bf16x8, ou);

  f32x16 o0, o1, lacc;
  #pragma unroll
  for (int r = 0; r < 16; r++) { o0[r] = 0.f; o1[r] = 0.f; lacc[r] = 0.f; }
  float m2 = -1e30f;

  #define STAGE(bufi, kv)                                                      \
    do {                                                                       \
      _Pragma("unroll")                                                        \
      for (int p = 0; p < 2; p++) {                                            \
        int loff = (w * 2 + p) * 1024 + lane * 16;                             \
        int krow = loff >> 7;                                                  \
        async16(Kb + (kv) * 128 + (loff ^ ((krow & 7) << 4)),                  \
                smem + (bufi) * 8192 + (w * 2 + p) * 1024);                    \
      }                                                                        \
      _Pragma("unroll")                                                        \
      for (int p = 0; p < 2; p++) {                                            \
        int loff = (w * 2 + p) * 1024 + lane * 16;                             \
        int d = loff >> 7;                                                     \
        int colb = loff & 127;                                                 \
        async16(Vb + (size_t)d * (S_LEN * 2) + (kv) * 2 +                      \
                    (colb ^ ((d & 7) << 4)),                                   \
                smem + 16384 + (bufi) * 8192 + (w * 2 + p) * 1024);            \
      }                                                                        \
    } while (0)

  STAGE(0, 0);
  __syncthreads();

  int buf = 0;
  for (int it = 0; it < S_LEN / 64; it++) {
    if (it < S_LEN / 64 - 1) STAGE(buf ^ 1, (it + 1) * 64);

    const char* Ks = smem + buf * 8192;
    const char* Vs = smem + 16384 + buf * 8192;

    f32x16 s0, s1;
    #pragma unroll
    for (int r = 0; r < 16; r++) { s0[r] = 0.f; s1[r] = 0.f; }

    __builtin_amdgcn_s_setprio(1);
    #pragma unroll
    for (int ks = 0; ks < 4; ks++) {
      int row = l32;
      bf16x8 ka = *(const bf16x8*)(Ks + ((row * 128 + ks * 32 + hi * 16) ^
                                         ((row & 7) << 4)));
      s0 = mfma32(ka, qf[ks], s0);
    }
    #pragma unroll
    for (int ks = 0; ks < 4; ks++) {
      int row = 32 + l32;
      bf16x8 ka = *(const bf16x8*)(Ks + ((row * 128 + ks * 32 + hi * 16) ^
                                         ((row & 7) << 4)));
      s1 = mfma32(ka, qf[ks], s1);
    }
    __builtin_amdgcn_s_setprio(0);

    // online softmax (log2 domain; Q pre-scaled), defer-max THR=8, tree max
    float t8[8];
    #pragma unroll
    for (int t = 0; t < 8; t++)
      t8[t] = fmaxf(fmaxf(s0[2 * t], s0[2 * t + 1]),
                    fmaxf(s1[2 * t], s1[2 * t + 1]));
    float t4a = fmaxf(t8[0], t8[1]), t4b = fmaxf(t8[2], t8[3]);
    float t4c = fmaxf(t8[4], t8[5]), t4d = fmaxf(t8[6], t8[7]);
    float mx = fmaxf(fmaxf(t4a, t4b), fmaxf(t4c, t4d));
    mx = fmaxf(mx, __shfl_xor(mx, 32));
    if (__any(mx > m2 + 8.0f)) {
      float mn = fmaxf(m2, mx);
      float sc = __builtin_amdgcn_exp2f(m2 - mn);
      lacc[0] *= sc;
      #pragma unroll
      for (int r = 0; r < 16; r++) { o0[r] *= sc; o1[r] *= sc; }
      m2 = mn;
    }
    #pragma unroll
    for (int r = 0; r < 16; r++) {
      s0[r] = __builtin_amdgcn_exp2f(s0[r] - m2);   // bounded by 2^8
      s1[r] = __builtin_amdgcn_exp2f(s1[r] - m2);
    }

    // P -> bf16 A-frags (keys 0..63) via cvt_pk + permlane32_swap
    unsigned c[8], e[8];
    #pragma unroll
    for (int t = 0; t < 8; t++) {
      asm("v_cvt_pk_bf16_f32 %0, %1, %2"
          : "=v"(c[t]) : "v"(s0[2 * t]), "v"(s0[2 * t + 1]));
      asm("v_cvt_pk_bf16_f32 %0, %1, %2"
          : "=v"(e[t]) : "v"(s1[2 * t]), "v"(s1[2 * t + 1]));
    }
    asm("v_permlane32_swap_b32 %0, %1" : "+v"(c[0]), "+v"(c[2]));
    asm("v_permlane32_swap_b32 %0, %1" : "+v"(c[1]), "+v"(c[3]));
    asm("v_permlane32_swap_b32 %0, %1" : "+v"(c[4]), "+v"(c[6]));
    asm("v_permlane32_swap_b32 %0, %1" : "+v"(c[5]), "+v"(c[7]));
    asm("v_permlane32_swap_b32 %0, %1" : "+v"(e[0]), "+v"(e[2]));
    asm("v_permlane32_swap_b32 %0, %1" : "+v"(e[1]), "+v"(e[3]));
    asm("v_permlane32_swap_b32 %0, %1" : "+v"(e[4]), "+v"(e[6]));
    asm("v_permlane32_swap_b32 %0, %1" : "+v"(e[5]), "+v"(e[7]));
    u32x4 t0 = {c[0], c[1], c[2], c[3]};
    u32x4 t1 = {c[4], c[5], c[6], c[7]};
    u32x4 t2 = {e[0], e[1], e[2], e[3]};
    u32x4 t3 = {e[4], e[5], e[6], e[7]};
    bf16x8 pa0 = __builtin_bit_cast(bf16x8, t0);
    bf16x8 pa1 = __builtin_bit_cast(bf16x8, t1);
    bf16x8 pa2 = __builtin_bit_cast(bf16x8, t2);
    bf16x8 pa3 = __builtin_bit_cast(bf16x8, t3);

    __builtin_amdgcn_s_setprio(1);
    lacc = mfma32(ones, pa0, lacc);
    lacc = mfma32(ones, pa1, lacc);
    lacc = mfma32(ones, pa2, lacc);
    lacc = mfma32(ones, pa3, lacc);
    {
      int row = l32;
      bf16x8 va0 = *(const bf16x8*)(Vs + ((row * 128 + 0 * 32 + hi * 16) ^ ((row & 7) << 4)));
      bf16x8 va1 = *(const bf16x8*)(Vs + ((row * 128 + 1 * 32 + hi * 16) ^ ((row & 7) << 4)));
      bf16x8 va2 = *(const bf16x8*)(Vs + ((row * 128 + 2 * 32 + hi * 16) ^ ((row & 7) << 4)));
      bf16x8 va3 = *(const bf16x8*)(Vs + ((row * 128 + 3 * 32 + hi * 16) ^ ((row & 7) << 4)));
      o0 = mfma32(va0, pa0, o0);
      o0 = mfma32(va1, pa1, o0);
      o0 = mfma32(va2, pa2, o0);
      o0 = mfma32(va3, pa3, o0);
    }
    {
      int row = 32 + l32;
      bf16x8 va0 = *(const bf16x8*)(Vs + ((row * 128 + 0 * 32 + hi * 16) ^ ((row & 7) << 4)));
      bf16x8 va1 = *(const bf16x8*)(Vs + ((row * 128 + 1 * 32 + hi * 16) ^ ((row & 7) << 4)));
      bf16x8 va2 = *(const bf16x8*)(Vs + ((row * 128 + 2 * 32 + hi * 16) ^ ((row & 7) << 4)));
      bf16x8 va3 = *(const bf16x8*)(Vs + ((row * 128 + 3 * 32 + hi * 16) ^ ((row & 7) << 4)));
      o1 = mfma32(va0, pa0, o1);
      o1 = mfma32(va1, pa1, o1);
      o1 = mfma32(va2, pa2, o1);
      o1 = mfma32(va3, pa3, o1);
    }
    __builtin_amdgcn_s_setprio(0);

    __syncthreads();
    buf ^= 1;
  }
  #undef STAGE

  float inv = 1.0f / lacc[0];   // full row sum (mfma sums both halves)

  // Epilogue: transpose O^T -> O via padded LDS (reuse smem), coalesced store.
  float* O = (float*)smem + w * (32 * 65);
  #pragma unroll
  for (int r = 0; r < 16; r++) {
    int d = (r & 3) + 8 * (r >> 2) + 4 * hi;
    O[l32 * 65 + d] = o0[r] * inv;
    O[l32 * 65 + 32 + d] = o1[r] * inv;
  }
  __syncthreads();
  const int qr = lane >> 1;
  const int coff = (lane & 1) * 32;
  const int b = bh >> 4, h = bh & 15;
  unsigned short* dst =
      &xout[((size_t)(b * S_LEN) + qb + qr) * D_EMBD + h * 64 + coff];
  #pragma unroll
  for (int t = 0; t < 4; t++) {
    u16x8 rr;
    #pragma unroll
    for (int j = 0; j < 8; j++)
      rr[j] = f2bf(O[qr * 65 + coff + t * 8 + j]);
    *(u16x8*)(dst + t * 8) = rr;
  }
}

extern "C" void kernel_launch(void* const* d_in, const int* in_sizes, int n_in,
                              void* d_out, int out_size, void* d_ws, size_t ws_size,
                              hipStream_t stream) {
  const float* q   = (const float*)d_in[0];
  const float* k   = (const float*)d_in[1];
  const float* v   = (const float*)d_in[2];
  const float* wqf = (const float*)d_in[3];
  const float* wkf = (const float*)d_in[4];
  const float* wvf = (const float*)d_in[5];
  const float* wof = (const float*)d_in[6];

  char* ws = (char*)d_ws;
  unsigned short* castbuf = (unsigned short*)(ws);                 // 16 MB
  unsigned short* qh = (unsigned short*)(ws + (16u << 20));        // 16 MB
  unsigned short* kh = (unsigned short*)(ws + (32u << 20));        // 16 MB
  unsigned short* vt = (unsigned short*)(ws + (48u << 20));        // 16 MB
  unsigned short* ax = (unsigned short*)(ws + (64u << 20));        // 16 MB
  unsigned short* wq = (unsigned short*)(ws + (80u << 20));        // 2 MB
  unsigned short* wk = wq + (1u << 20);
  unsigned short* wv = wk + (1u << 20);
  unsigned short* wo = wv + (1u << 20);

  const int MK8 = M_TOT * D_EMBD / 8;   // 1048576

  const float QSCALE = 0.125f * 1.4426950408889634f;

  cast_w4_kernel<<<2048, 256, 0, stream>>>(wqf, wkf, wvf, wof, wq);

  dim3 gg(D_EMBD / 128, M_TOT / 128);  // (8, 64)

  cast_bf16_kernel<<<MK8 / 256, 256, 0, stream>>>(q, castbuf, MK8);
  gemm_bt<0><<<gg, 256, 0, stream>>>(castbuf, wq, qh, QSCALE, M_TOT, D_EMBD, D_EMBD);
  cast_bf16_kernel<<<MK8 / 256, 256, 0, stream>>>(k, castbuf, MK8);
  gemm_bt<0><<<gg, 256, 0, stream>>>(castbuf, wk, kh, 1.0f, M_TOT, D_EMBD, D_EMBD);
  cast_bf16_kernel<<<MK8 / 256, 256, 0, stream>>>(v, castbuf, MK8);
  gemm_bt<2><<<gg, 256, 0, stream>>>(castbuf, wv, vt, 1.0f, M_TOT, D_EMBD, D_EMBD);

  attn_kernel<<<1024, 256, 0, stream>>>(qh, kh, vt, ax);

  gemm_bt<1><<<gg, 256, 0, stream>>>(ax, wo, d_out, 1.0f, M_TOT, D_EMBD, D_EMBD);
}